// Round 1
// baseline (377.662 us; speedup 1.0000x reference)
//
#include <hip/hip_runtime.h>
#include <hip/hip_bf16.h>

#define DIM 2048
#define SEQ 2048
#define NH 32
#define HD 64
#define NKV 8
#define QKV_LD 3072

typedef __attribute__((ext_vector_type(8))) short bf16x8;
typedef __attribute__((ext_vector_type(4))) float f32x4;
typedef unsigned short ushort_t;

__device__ inline unsigned short f2bf(float f) {
    union { float f; unsigned int u; } v; v.f = f;
    unsigned int r = v.u + 0x7fffu + ((v.u >> 16) & 1u);
    return (unsigned short)(r >> 16);
}
__device__ inline float bf2f(ushort_t u) {
    union { unsigned int u; float f; } v; v.u = ((unsigned int)u) << 16; return v.f;
}

// async global->LDS, 16B per lane. LDS dest is wave-uniform base + lane*16.
__device__ inline void async_cp16(const void* g, void* l) {
    __builtin_amdgcn_global_load_lds(
        (const __attribute__((address_space(1))) unsigned int*)g,
        (__attribute__((address_space(3))) unsigned int*)l, 16, 0, 0);
}
__device__ inline void lgkm_fence() {
    __asm__ volatile("s_waitcnt lgkmcnt(0)" ::: "memory");
}

// ---------------------------------------------------------------------------
// x fp32 -> bf16 (4 elems/thread)
// ---------------------------------------------------------------------------
__global__ __launch_bounds__(256) void convert_kernel(
    const float* __restrict__ X, ushort_t* __restrict__ Xb)
{
    int i = (blockIdx.x * 256 + threadIdx.x) * 4;
    float4 v = *(const float4*)(X + i);
    ushort_t o[4] = { f2bf(v.x), f2bf(v.y), f2bf(v.z), f2bf(v.w) };
    *(uint2*)(Xb + i) = *(uint2*)o;
}

// ---------------------------------------------------------------------------
// W fp32 [2048][N] -> WT bf16 [N][2048] (transpose + convert), 64x64 tiles.
// ---------------------------------------------------------------------------
__global__ __launch_bounds__(256) void transpose_kernel(
    const float* __restrict__ W, ushort_t* __restrict__ WT, int N)
{
    __shared__ __align__(16) ushort_t tile[64][72];
    const int n0 = blockIdx.x * 64, k0 = blockIdx.y * 64;
    const int t = threadIdx.x;
    {
        const int tk = t >> 4;
        const int tn = (t & 15) * 4;
        #pragma unroll
        for (int i = 0; i < 4; i++) {
            const int k = tk + i * 16;
            float4 v = *(const float4*)(W + (size_t)(k0 + k) * N + n0 + tn);
            tile[tn + 0][k] = f2bf(v.x);
            tile[tn + 1][k] = f2bf(v.y);
            tile[tn + 2][k] = f2bf(v.z);
            tile[tn + 3][k] = f2bf(v.w);
        }
    }
    __syncthreads();
    {
        const int tn = t >> 2;
        const int tk = (t & 3) * 16;
        uint4 a = *(const uint4*)&tile[tn][tk];
        uint4 b = *(const uint4*)&tile[tn][tk + 8];
        ushort_t* dst = WT + (size_t)(n0 + tn) * DIM + k0 + tk;
        *(uint4*)dst = a;
        *(uint4*)(dst + 8) = b;
    }
}

// ---------------------------------------------------------------------------
// GEMM m97-style: C[M,N] = A[M,K](bf16) * BT[N,K](bf16)^T.
// 128x128 tile / 256 threads, BK=32, global_load_lds staging (unpadded LDS).
// Grid (N/128, M/128). OUT_F32: fp32 epilogue to d_out.
// ---------------------------------------------------------------------------
template<int OUT_F32>
__global__ __launch_bounds__(256) void gemm_kernel(
    const ushort_t* __restrict__ A, const ushort_t* __restrict__ BT,
    void* __restrict__ Cout, int K, int lda, int ldo)
{
    __shared__ __align__(16) ushort_t sA[128 * 32];
    __shared__ __align__(16) ushort_t sB[128 * 32];
    const int tn = blockIdx.x * 128, tm = blockIdx.y * 128;
    const int t = threadIdx.x, wave = t >> 6, lane = t & 63;
    const int m16 = lane & 15, quad = lane >> 4;
    const int wr = (wave >> 1) * 64, wc = (wave & 1) * 64;
    const int srow = lane >> 2;
    const int sce = (lane & 3) * 8;

    f32x4 acc[4][4] = {};

    for (int k0 = 0; k0 < K; k0 += 32) {
        __syncthreads();
        #pragma unroll
        for (int p = 0; p < 2; p++) {
            const int j = wave * 2 + p;
            const int row = j * 16 + srow;
            async_cp16(A  + (size_t)(tm + row) * lda + k0 + sce, &sA[j * 512]);
            async_cp16(BT + (size_t)(tn + row) * K   + k0 + sce, &sB[j * 512]);
        }
        __syncthreads();
        bf16x8 af[4], bf[4];
        #pragma unroll
        for (int mt = 0; mt < 4; mt++)
            af[mt] = *(const bf16x8*)&sA[(wr + mt * 16 + m16) * 32 + quad * 8];
        #pragma unroll
        for (int nt = 0; nt < 4; nt++)
            bf[nt] = *(const bf16x8*)&sB[(wc + nt * 16 + m16) * 32 + quad * 8];
        #pragma unroll
        for (int mt = 0; mt < 4; mt++)
            #pragma unroll
            for (int nt = 0; nt < 4; nt++)
                acc[mt][nt] = __builtin_amdgcn_mfma_f32_16x16x32_bf16(af[mt], bf[nt], acc[mt][nt], 0, 0, 0);
    }

    #pragma unroll
    for (int mt = 0; mt < 4; mt++) {
        const int row = tm + wr + mt * 16 + quad * 4;
        #pragma unroll
        for (int nt = 0; nt < 4; nt++) {
            const int col = tn + wc + nt * 16 + m16;
            #pragma unroll
            for (int r = 0; r < 4; r++) {
                if (OUT_F32)
                    ((float*)Cout)[(size_t)(row + r) * ldo + col] = acc[mt][nt][r];
                else
                    ((ushort_t*)Cout)[(size_t)(row + r) * ldo + col] = f2bf(acc[mt][nt][r]);
            }
        }
    }
}

// ---------------------------------------------------------------------------
// RoPE, lane-per-element: one wave per 64-elem head slice, 1 shuffle/lane.
// lane l<32:  out = e[l]*cos(ang_l)      - e[2l+1]*sin(ang_l)
// lane l>=32: out = e[l]*cos(ang_{l-32}) + e[2(l-32)]*sin(ang_{l-32})
// Slices: idx in [0, SEQ*40): hh<32 -> Q (in place), else K -> Kr[kvh][s][64].
// ---------------------------------------------------------------------------
__global__ __launch_bounds__(256) void rope_kernel(ushort_t* qkv, ushort_t* __restrict__ Kr)
{
    const int gid = blockIdx.x * 256 + threadIdx.x;
    const int lane = gid & 63;
    const int idx = gid >> 6;              // slice index
    const int s = idx / 40;
    const int hh = idx - s * 40;

    const ushort_t* src;
    ushort_t* dst;
    if (hh < 32) {
        dst = qkv + (size_t)s * QKV_LD + hh * 64;
        src = dst;
    } else {
        src = qkv + (size_t)s * QKV_LD + 2048 + (hh - 32) * 64;
        dst = Kr + ((size_t)(hh - 32) * SEQ + s) * 64;
    }

    const float e = bf2f(src[lane]);
    const int i = lane & 31;
    const float freq = __expf(-(float)i * 0.28782313662425572f);  // ln(10000)/32
    const float ang = (float)s * freq;
    const float cv = cosf(ang), sv = sinf(ang);
    const int partner = (lane < 32) ? (2 * lane + 1) : (2 * (lane - 32));
    const float y = __shfl(e, partner, 64);
    const float out = (lane < 32) ? (e * cv - y * sv) : (e * cv + y * sv);
    dst[lane] = f2bf(out);
}

// ---------------------------------------------------------------------------
// V transpose (tiled through LDS): Vt[kvh][d][s] = qkv[s][2560+kvh*64+d]
// ---------------------------------------------------------------------------
__global__ __launch_bounds__(256) void vtrans_kernel(
    const ushort_t* __restrict__ qkv, ushort_t* __restrict__ Vt)
{
    __shared__ __align__(16) ushort_t tile[64][72];
    const int kvh = blockIdx.x & 7;
    const int s0 = (blockIdx.x >> 3) * 64;
    const int t = threadIdx.x;
    {
        const int sr = t >> 3;
        const int d8 = (t & 7) * 8;
        #pragma unroll
        for (int i = 0; i < 2; i++) {
            const int s = sr + i * 32;
            ushort_t tmp[8];
            *(uint4*)tmp = *(const uint4*)(qkv + (size_t)(s0 + s) * QKV_LD + 2560 + kvh * 64 + d8);
            #pragma unroll
            for (int j = 0; j < 8; j++) tile[d8 + j][s] = tmp[j];
        }
    }
    __syncthreads();
    {
        const int dr = t >> 3;
        const int s8 = (t & 7) * 8;
        #pragma unroll
        for (int i = 0; i < 2; i++) {
            const int d = dr + i * 32;
            *(uint4*)(Vt + ((size_t)kvh * 64 + d) * SEQ + s0 + s8) = *(const uint4*)&tile[d][s8];
        }
    }
}

// ---------------------------------------------------------------------------
// Flash attention, S^T orientation, occupancy-first restructure.
// Block = 256 threads (4 waves). Each wave owns ONE 16-query strip of a
// 64-query tile; no block barriers (waves fully independent). Grid =
// 32 q-tiles x 32 heads = 1024 blocks = 4096 waves -> 16 waves/CU (4/SIMD),
// vs 1 wave/SIMD before (OccupancyPercent was 9%). Work imbalance handled
// by heavy-first block ordering + 4 resident blocks/CU.
// K/V read from L2; P^T via per-wave double-buffered LDS (fence covers WAR).
// ---------------------------------------------------------------------------
#define SPS 80   // sP row stride (ushorts)
__global__ __launch_bounds__(256, 4) void attn_kernel(
    ushort_t* qkv, const ushort_t* __restrict__ Kr, const ushort_t* __restrict__ Vt)
{
    __shared__ __align__(16) ushort_t sP[4][2][16 * SPS];   // [wave][parity]

    const int t = threadIdx.x, wave = t >> 6, lane = t & 63;
    const int m16 = lane & 15, quad = lane >> 4;
    const int h = blockIdx.x & 31;
    const int qt = 31 - (blockIdx.x >> 5);     // heavy tiles dispatched first
    const int kvh = h >> 2;

    const ushort_t* Krh = Kr + (size_t)kvh * SEQ * 64;   // [s][d]
    const ushort_t* Vth = Vt + (size_t)kvh * 64 * SEQ;   // [d][s]

    const int qb = qt * 64;
    const int q0 = qb + wave * 16;             // this wave's 16-query strip
    const int qi = q0 + m16;                   // this lane's query
    const int nkt = qt + 1;

    // Q fragments (B-operand layout): rows q0+m16, d = quad*8+j
    bf16x8 qf[2];
    {
        const ushort_t* qp = qkv + (size_t)qi * QKV_LD + h * 64 + quad * 8;
        qf[0] = *(const bf16x8*)qp;
        qf[1] = *(const bf16x8*)(qp + 32);
    }

    f32x4 oacc[4] = {};                        // O^T: col=q(m16), row=d
    float m_run = -1e30f;
    float l_run = 0.f;

    for (int kt = 0; kt < nkt; kt++) {
        const int kbase = kt * 64;
        const bool domask = (kt == nkt - 1);

        // K fragments; consumed by QK^T, dead before V arrives (reg pressure)
        bf16x8 kf[4][2];
        #pragma unroll
        for (int knt = 0; knt < 4; knt++) {
            const ushort_t* kp = Krh + (size_t)(kbase + knt * 16 + m16) * 64 + quad * 8;
            kf[knt][0] = *(const bf16x8*)kp;
            kf[knt][1] = *(const bf16x8*)(kp + 32);
        }

        f32x4 sc[4] = {};
        #pragma unroll
        for (int knt = 0; knt < 4; knt++) {
            sc[knt] = __builtin_amdgcn_mfma_f32_16x16x32_bf16(kf[knt][0], qf[0], sc[knt], 0, 0, 0);
            sc[knt] = __builtin_amdgcn_mfma_f32_16x16x32_bf16(kf[knt][1], qf[1], sc[knt], 0, 0, 0);
        }

        // Issue V loads now: latency hides under the softmax VALU chain.
        bf16x8 vf[4][2];
        #pragma unroll
        for (int nt = 0; nt < 4; nt++) {
            const ushort_t* vp = Vth + (size_t)(nt * 16 + m16) * SEQ + kbase + quad * 8;
            vf[nt][0] = *(const bf16x8*)vp;
            vf[nt][1] = *(const bf16x8*)(vp + 32);
        }

        float s[16];
        #pragma unroll
        for (int knt = 0; knt < 4; knt++)
            #pragma unroll
            for (int r = 0; r < 4; r++) {
                float v = sc[knt][r] * 0.125f;
                if (domask && (kbase + knt * 16 + quad * 4 + r > qi)) v = -1e30f;
                s[knt * 4 + r] = v;
            }

        float rmax = s[0];
        #pragma unroll
        for (int i = 1; i < 16; i++) rmax = fmaxf(rmax, s[i]);
        rmax = fmaxf(rmax, __shfl_xor(rmax, 16, 64));
        rmax = fmaxf(rmax, __shfl_xor(rmax, 32, 64));

        const float mnew = fmaxf(m_run, rmax);
        const float alpha = __expf(m_run - mnew);
        m_run = mnew;

        float ps = 0.f;
        #pragma unroll
        for (int i = 0; i < 16; i++) { s[i] = __expf(s[i] - mnew); ps += s[i]; }
        ps += __shfl_xor(ps, 16, 64);
        ps += __shfl_xor(ps, 32, 64);
        l_run = l_run * alpha + ps;

        // ---- P^T -> per-wave dbuf LDS (col-major sP[q][key]) ----
        ushort_t* sPw = sP[wave][kt & 1];
        #pragma unroll
        for (int knt = 0; knt < 4; knt++) {
            unsigned int u0 = (unsigned int)f2bf(s[knt * 4 + 0]) | ((unsigned int)f2bf(s[knt * 4 + 1]) << 16);
            unsigned int u1 = (unsigned int)f2bf(s[knt * 4 + 2]) | ((unsigned int)f2bf(s[knt * 4 + 3]) << 16);
            uint2 pk; pk.x = u0; pk.y = u1;
            *(uint2*)&sPw[m16 * SPS + knt * 16 + quad * 4] = pk;
        }
        lgkm_fence();   // writes visible; also drains prior buffer's reads
        bf16x8 pf0 = *(const bf16x8*)&sPw[m16 * SPS + quad * 8];
        bf16x8 pf1 = *(const bf16x8*)&sPw[m16 * SPS + 32 + quad * 8];

        // ---- O^T += V^T @ P^T ----
        #pragma unroll
        for (int nt = 0; nt < 4; nt++) {
            #pragma unroll
            for (int r = 0; r < 4; r++) oacc[nt][r] *= alpha;
            oacc[nt] = __builtin_amdgcn_mfma_f32_16x16x32_bf16(vf[nt][0], pf0, oacc[nt], 0, 0, 0);
            oacc[nt] = __builtin_amdgcn_mfma_f32_16x16x32_bf16(vf[nt][1], pf1, oacc[nt], 0, 0, 0);
        }
    }

    // ---- epilogue: O[q][h*64+d] = O^T/l ----
    {
        const float rl = 1.f / l_run;
        #pragma unroll
        for (int nt = 0; nt < 4; nt++) {
            ushort_t pk[4];
            #pragma unroll
            for (int r = 0; r < 4; r++) pk[r] = f2bf(oacc[nt][r] * rl);
            *(uint2*)&qkv[(size_t)qi * QKV_LD + h * 64 + nt * 16 + quad * 4] = *(uint2*)pk;
        }
    }
}

// ---------------------------------------------------------------------------
extern "C" void kernel_launch(void* const* d_in, const int* in_sizes, int n_in,
                              void* d_out, int out_size, void* d_ws, size_t ws_size,
                              hipStream_t stream)
{
    const float* x  = (const float*)d_in[0];
    // d_in[1] = mask (int32) — causal, handled analytically
    const float* wq = (const float*)d_in[2];
    const float* wk = (const float*)d_in[3];
    const float* wv = (const float*)d_in[4];
    const float* wo = (const float*)d_in[5];

    ushort_t* WT  = (ushort_t*)d_ws;                    // [3072][2048] bf16
    ushort_t* xb  = WT + (size_t)3072 * 2048;           // [2048][2048] bf16
    ushort_t* woT = xb;                                 // alias: xb dead after QKV GEMM
    ushort_t* qkv = xb + (size_t)2048 * 2048;           // [2048][3072] bf16
    ushort_t* Kr  = qkv + (size_t)SEQ * QKV_LD;         // [8][2048][64]
    ushort_t* Vt  = Kr + (size_t)NKV * SEQ * HD;        // [8][64][2048]

    dim3 blk(256);

    convert_kernel<<<(DIM * SEQ) / 1024, blk, 0, stream>>>(x, xb);
    transpose_kernel<<<dim3(32, 32), blk, 0, stream>>>(wq, WT, 2048);
    transpose_kernel<<<dim3(8, 32),  blk, 0, stream>>>(wk, WT + (size_t)2048 * 2048, 512);
    transpose_kernel<<<dim3(8, 32),  blk, 0, stream>>>(wv, WT + (size_t)2560 * 2048, 512);

    // Fused QKV projection: [2048,2048] x [2048,3072] -> qkv
    gemm_kernel<0><<<dim3(QKV_LD / 128, SEQ / 128), blk, 0, stream>>>(xb, WT, qkv, DIM, DIM, QKV_LD);

    // wo transpose (reuses xb region — must follow the QKV GEMM)
    transpose_kernel<<<dim3(32, 32), blk, 0, stream>>>(wo, woT, 2048);

    // RoPE: SEQ*40 slices, one wave each
    rope_kernel<<<(SEQ * 40 * 64) / 256, blk, 0, stream>>>(qkv, Kr);
    vtrans_kernel<<<NKV * (SEQ / 64), blk, 0, stream>>>(qkv, Vt);

    // Attention: 32 q-tiles x 32 heads, 4 waves/block (one strip each)
    attn_kernel<<<32 * NH, dim3(256), 0, stream>>>(qkv, Kr, Vt);

    // Output projection -> d_out fp32
    gemm_kernel<1><<<dim3(DIM / 128, SEQ / 128), blk, 0, stream>>>(qkv, woT, d_out, DIM, QKV_LD, DIM);
}

// Round 2
// 301.502 us; speedup vs baseline: 1.2526x; 1.2526x over previous
//
#include <hip/hip_runtime.h>
#include <hip/hip_bf16.h>

#define DIM 2048
#define SEQ 2048
#define NH 32
#define HD 64
#define NKV 8
#define QKV_LD 3072

typedef __attribute__((ext_vector_type(8))) short bf16x8;
typedef __attribute__((ext_vector_type(4))) float f32x4;
typedef unsigned short ushort_t;

__device__ inline unsigned short f2bf(float f) {
    union { float f; unsigned int u; } v; v.f = f;
    unsigned int r = v.u + 0x7fffu + ((v.u >> 16) & 1u);
    return (unsigned short)(r >> 16);
}
__device__ inline float bf2f(ushort_t u) {
    union { unsigned int u; float f; } v; v.u = ((unsigned int)u) << 16; return v.f;
}

// async global->LDS, 16B per lane. LDS dest is wave-uniform base + lane*16.
__device__ inline void async_cp16(const void* g, void* l) {
    __builtin_amdgcn_global_load_lds(
        (const __attribute__((address_space(1))) unsigned int*)g,
        (__attribute__((address_space(3))) unsigned int*)l, 16, 0, 0);
}
__device__ inline void lgkm_fence() {
    __asm__ volatile("s_waitcnt lgkmcnt(0)" ::: "memory");
}

// ---------------------------------------------------------------------------
// x fp32 -> bf16 (4 elems/thread)
// ---------------------------------------------------------------------------
__global__ __launch_bounds__(256) void convert_kernel(
    const float* __restrict__ X, ushort_t* __restrict__ Xb)
{
    int i = (blockIdx.x * 256 + threadIdx.x) * 4;
    float4 v = *(const float4*)(X + i);
    ushort_t o[4] = { f2bf(v.x), f2bf(v.y), f2bf(v.z), f2bf(v.w) };
    *(uint2*)(Xb + i) = *(uint2*)o;
}

// ---------------------------------------------------------------------------
// W fp32 [2048][N] -> WT bf16 [N][2048] (transpose + convert), 64x64 tiles.
// ---------------------------------------------------------------------------
__global__ __launch_bounds__(256) void transpose_kernel(
    const float* __restrict__ W, ushort_t* __restrict__ WT, int N)
{
    __shared__ __align__(16) ushort_t tile[64][72];
    const int n0 = blockIdx.x * 64, k0 = blockIdx.y * 64;
    const int t = threadIdx.x;
    {
        const int tk = t >> 4;
        const int tn = (t & 15) * 4;
        #pragma unroll
        for (int i = 0; i < 4; i++) {
            const int k = tk + i * 16;
            float4 v = *(const float4*)(W + (size_t)(k0 + k) * N + n0 + tn);
            tile[tn + 0][k] = f2bf(v.x);
            tile[tn + 1][k] = f2bf(v.y);
            tile[tn + 2][k] = f2bf(v.z);
            tile[tn + 3][k] = f2bf(v.w);
        }
    }
    __syncthreads();
    {
        const int tn = t >> 2;
        const int tk = (t & 3) * 16;
        uint4 a = *(const uint4*)&tile[tn][tk];
        uint4 b = *(const uint4*)&tile[tn][tk + 8];
        ushort_t* dst = WT + (size_t)(n0 + tn) * DIM + k0 + tk;
        *(uint4*)dst = a;
        *(uint4*)(dst + 8) = b;
    }
}

// ---------------------------------------------------------------------------
// GEMM m97-style: C[M,N] = A[M,K](bf16) * BT[N,K](bf16)^T.
// 128x128 tile / 256 threads, BK=32, global_load_lds staging (unpadded LDS).
// Grid (N/128, M/128). OUT_F32: fp32 epilogue to d_out.
// ---------------------------------------------------------------------------
template<int OUT_F32>
__global__ __launch_bounds__(256) void gemm_kernel(
    const ushort_t* __restrict__ A, const ushort_t* __restrict__ BT,
    void* __restrict__ Cout, int K, int lda, int ldo)
{
    __shared__ __align__(16) ushort_t sA[128 * 32];
    __shared__ __align__(16) ushort_t sB[128 * 32];
    const int tn = blockIdx.x * 128, tm = blockIdx.y * 128;
    const int t = threadIdx.x, wave = t >> 6, lane = t & 63;
    const int m16 = lane & 15, quad = lane >> 4;
    const int wr = (wave >> 1) * 64, wc = (wave & 1) * 64;
    const int srow = lane >> 2;
    const int sce = (lane & 3) * 8;

    f32x4 acc[4][4] = {};

    for (int k0 = 0; k0 < K; k0 += 32) {
        __syncthreads();
        #pragma unroll
        for (int p = 0; p < 2; p++) {
            const int j = wave * 2 + p;
            const int row = j * 16 + srow;
            async_cp16(A  + (size_t)(tm + row) * lda + k0 + sce, &sA[j * 512]);
            async_cp16(BT + (size_t)(tn + row) * K   + k0 + sce, &sB[j * 512]);
        }
        __syncthreads();
        bf16x8 af[4], bf[4];
        #pragma unroll
        for (int mt = 0; mt < 4; mt++)
            af[mt] = *(const bf16x8*)&sA[(wr + mt * 16 + m16) * 32 + quad * 8];
        #pragma unroll
        for (int nt = 0; nt < 4; nt++)
            bf[nt] = *(const bf16x8*)&sB[(wc + nt * 16 + m16) * 32 + quad * 8];
        #pragma unroll
        for (int mt = 0; mt < 4; mt++)
            #pragma unroll
            for (int nt = 0; nt < 4; nt++)
                acc[mt][nt] = __builtin_amdgcn_mfma_f32_16x16x32_bf16(af[mt], bf[nt], acc[mt][nt], 0, 0, 0);
    }

    #pragma unroll
    for (int mt = 0; mt < 4; mt++) {
        const int row = tm + wr + mt * 16 + quad * 4;
        #pragma unroll
        for (int nt = 0; nt < 4; nt++) {
            const int col = tn + wc + nt * 16 + m16;
            #pragma unroll
            for (int r = 0; r < 4; r++) {
                if (OUT_F32)
                    ((float*)Cout)[(size_t)(row + r) * ldo + col] = acc[mt][nt][r];
                else
                    ((ushort_t*)Cout)[(size_t)(row + r) * ldo + col] = f2bf(acc[mt][nt][r]);
            }
        }
    }
}

// ---------------------------------------------------------------------------
// RoPE, lane-per-element: one wave per 64-elem head slice, 1 shuffle/lane.
// ---------------------------------------------------------------------------
__global__ __launch_bounds__(256) void rope_kernel(ushort_t* qkv, ushort_t* __restrict__ Kr)
{
    const int gid = blockIdx.x * 256 + threadIdx.x;
    const int lane = gid & 63;
    const int idx = gid >> 6;              // slice index
    const int s = idx / 40;
    const int hh = idx - s * 40;

    const ushort_t* src;
    ushort_t* dst;
    if (hh < 32) {
        dst = qkv + (size_t)s * QKV_LD + hh * 64;
        src = dst;
    } else {
        src = qkv + (size_t)s * QKV_LD + 2048 + (hh - 32) * 64;
        dst = Kr + ((size_t)(hh - 32) * SEQ + s) * 64;
    }

    const float e = bf2f(src[lane]);
    const int i = lane & 31;
    const float freq = __expf(-(float)i * 0.28782313662425572f);  // ln(10000)/32
    const float ang = (float)s * freq;
    const float cv = cosf(ang), sv = sinf(ang);
    const int partner = (lane < 32) ? (2 * lane + 1) : (2 * (lane - 32));
    const float y = __shfl(e, partner, 64);
    const float out = (lane < 32) ? (e * cv - y * sv) : (e * cv + y * sv);
    dst[lane] = f2bf(out);
}

// ---------------------------------------------------------------------------
// V transpose (tiled through LDS): Vt[kvh][d][s] = qkv[s][2560+kvh*64+d]
// ---------------------------------------------------------------------------
__global__ __launch_bounds__(256) void vtrans_kernel(
    const ushort_t* __restrict__ qkv, ushort_t* __restrict__ Vt)
{
    __shared__ __align__(16) ushort_t tile[64][72];
    const int kvh = blockIdx.x & 7;
    const int s0 = (blockIdx.x >> 3) * 64;
    const int t = threadIdx.x;
    {
        const int sr = t >> 3;
        const int d8 = (t & 7) * 8;
        #pragma unroll
        for (int i = 0; i < 2; i++) {
            const int s = sr + i * 32;
            ushort_t tmp[8];
            *(uint4*)tmp = *(const uint4*)(qkv + (size_t)(s0 + s) * QKV_LD + 2560 + kvh * 64 + d8);
            #pragma unroll
            for (int j = 0; j < 8; j++) tile[d8 + j][s] = tmp[j];
        }
    }
    __syncthreads();
    {
        const int dr = t >> 3;
        const int s8 = (t & 7) * 8;
        #pragma unroll
        for (int i = 0; i < 2; i++) {
            const int d = dr + i * 32;
            *(uint4*)(Vt + ((size_t)kvh * 64 + d) * SEQ + s0 + s8) = *(const uint4*)&tile[d][s8];
        }
    }
}

// ---------------------------------------------------------------------------
// Flash attention, S^T orientation.
// Block = 512 threads (8 waves), NO block barriers (waves independent).
// Waves 0-3 process band 15-p (128 queries), waves 4-7 band p: per-CU total
// work is EXACTLY uniform (34 k-tiles x 4 waves) with grid 256 = 1 block/CU.
// Each wave owns 2 query strips (qa=0 lower 64, qa=1 upper 64) so each K/V
// fragment load feeds 32 MFMAs; next-tile K is prefetched into registers so
// its L2 latency hides under the softmax+PV chain of the current tile.
// K/V read from L2; P^T via per-wave double-buffered LDS.
// ---------------------------------------------------------------------------
#define SPS 80   // sP row stride (ushorts)
__global__ __launch_bounds__(512, 2) void attn_kernel(
    ushort_t* qkv, const ushort_t* __restrict__ Kr, const ushort_t* __restrict__ Vt)
{
    __shared__ __align__(16) ushort_t sP[8][2][16 * SPS];   // [wave][strip]

    const int t = threadIdx.x, wave = t >> 6, lane = t & 63;
    const int m16 = lane & 15, quad = lane >> 4;
    const int h = blockIdx.x & 31;
    const int p = blockIdx.x >> 5;             // pair index 0..7
    const int grp = wave >> 2;                 // 0: heavy band, 1: light band
    const int w4 = wave & 3;
    const int band = grp ? p : 15 - p;         // 128-query band
    const int kvh = h >> 2;

    const ushort_t* Krh = Kr + (size_t)kvh * SEQ * 64;   // [s][d]
    const ushort_t* Vth = Vt + (size_t)kvh * 64 * SEQ;   // [d][s]

    const int nkt = band * 2 + 2;

    // Two 16-query strips per wave: qa=0 -> lower 64 of band, qa=1 -> upper.
    int qi[2];
    bf16x8 qf[2][2];
    #pragma unroll
    for (int qa = 0; qa < 2; qa++) {
        qi[qa] = band * 128 + (w4 + qa * 4) * 16 + m16;
        const ushort_t* qp = qkv + (size_t)qi[qa] * QKV_LD + h * 64 + quad * 8;
        qf[qa][0] = *(const bf16x8*)qp;
        qf[qa][1] = *(const bf16x8*)(qp + 32);
    }

    f32x4 oacc[2][4] = {};                  // O^T: col=q(m16), row=d
    float m_run[2] = { -1e30f, -1e30f };
    float l_run[2] = { 0.f, 0.f };

    // Prologue: K fragments for tile 0 (only load that pays full latency).
    bf16x8 kf[4][2];
    #pragma unroll
    for (int knt = 0; knt < 4; knt++) {
        const ushort_t* kp = Krh + (size_t)(knt * 16 + m16) * 64 + quad * 8;
        kf[knt][0] = *(const bf16x8*)kp;
        kf[knt][1] = *(const bf16x8*)(kp + 32);
    }

    for (int kt = 0; kt < nkt; kt++) {
        const int kbase = kt * 64;
        const bool last = (kt == nkt - 1);

        // ---- QK^T for both strips while kf is live ----
        f32x4 sc[2][4] = {};
        #pragma unroll
        for (int qa = 0; qa < 2; qa++) {
            if (qa == 0 && last) continue;   // last tile fully masked for lower strip
            #pragma unroll
            for (int knt = 0; knt < 4; knt++) {
                sc[qa][knt] = __builtin_amdgcn_mfma_f32_16x16x32_bf16(kf[knt][0], qf[qa][0], sc[qa][knt], 0, 0, 0);
                sc[qa][knt] = __builtin_amdgcn_mfma_f32_16x16x32_bf16(kf[knt][1], qf[qa][1], sc[qa][knt], 0, 0, 0);
            }
        }

        // ---- V loads for this tile (consumed after softmax) ----
        bf16x8 vf[4][2];
        #pragma unroll
        for (int nt = 0; nt < 4; nt++) {
            const ushort_t* vp = Vth + (size_t)(nt * 16 + m16) * SEQ + kbase + quad * 8;
            vf[nt][0] = *(const bf16x8*)vp;
            vf[nt][1] = *(const bf16x8*)(vp + 32);
        }
        // ---- K prefetch for next tile (consumed next iteration) ----
        if (!last) {
            #pragma unroll
            for (int knt = 0; knt < 4; knt++) {
                const ushort_t* kp = Krh + (size_t)(kbase + 64 + knt * 16 + m16) * 64 + quad * 8;
                kf[knt][0] = *(const bf16x8*)kp;
                kf[knt][1] = *(const bf16x8*)(kp + 32);
            }
        }

        // ---- softmax + PV per strip ----
        #pragma unroll
        for (int qa = 0; qa < 2; qa++) {
            if (qa == 0 && last) continue;
            const bool domask = (qa == 0) ? (kt == nkt - 2) : last;

            float s[16];
            #pragma unroll
            for (int knt = 0; knt < 4; knt++)
                #pragma unroll
                for (int r = 0; r < 4; r++) {
                    float v = sc[qa][knt][r] * 0.125f;
                    if (domask && (kbase + knt * 16 + quad * 4 + r > qi[qa])) v = -1e30f;
                    s[knt * 4 + r] = v;
                }

            // depth-4 max tree (fusable to v_max3)
            float x0 = fmaxf(s[0], s[1]),  x1 = fmaxf(s[2], s[3]);
            float x2 = fmaxf(s[4], s[5]),  x3 = fmaxf(s[6], s[7]);
            float x4 = fmaxf(s[8], s[9]),  x5 = fmaxf(s[10], s[11]);
            float x6 = fmaxf(s[12], s[13]), x7 = fmaxf(s[14], s[15]);
            float rmax = fmaxf(fmaxf(fmaxf(x0, x1), fmaxf(x2, x3)),
                               fmaxf(fmaxf(x4, x5), fmaxf(x6, x7)));
            rmax = fmaxf(rmax, __shfl_xor(rmax, 16, 64));
            rmax = fmaxf(rmax, __shfl_xor(rmax, 32, 64));

            const float mnew = fmaxf(m_run[qa], rmax);
            const float alpha = __expf(m_run[qa] - mnew);
            m_run[qa] = mnew;

            #pragma unroll
            for (int i = 0; i < 16; i++) s[i] = __expf(s[i] - mnew);
            // depth-4 sum tree
            float y0 = s[0] + s[1],  y1 = s[2] + s[3];
            float y2 = s[4] + s[5],  y3 = s[6] + s[7];
            float y4 = s[8] + s[9],  y5 = s[10] + s[11];
            float y6 = s[12] + s[13], y7 = s[14] + s[15];
            float ps = ((y0 + y1) + (y2 + y3)) + ((y4 + y5) + (y6 + y7));
            ps += __shfl_xor(ps, 16, 64);
            ps += __shfl_xor(ps, 32, 64);
            l_run[qa] = l_run[qa] * alpha + ps;

            // ---- P^T -> per-wave dbuf LDS (col-major sP[q][key]) ----
            ushort_t* sPw = sP[wave][qa];
            #pragma unroll
            for (int knt = 0; knt < 4; knt++) {
                unsigned int u0 = (unsigned int)f2bf(s[knt * 4 + 0]) | ((unsigned int)f2bf(s[knt * 4 + 1]) << 16);
                unsigned int u1 = (unsigned int)f2bf(s[knt * 4 + 2]) | ((unsigned int)f2bf(s[knt * 4 + 3]) << 16);
                uint2 pk; pk.x = u0; pk.y = u1;
                *(uint2*)&sPw[m16 * SPS + knt * 16 + quad * 4] = pk;
            }
            lgkm_fence();   // writes visible; also drains prior reads (WAR)
            bf16x8 pf0 = *(const bf16x8*)&sPw[m16 * SPS + quad * 8];
            bf16x8 pf1 = *(const bf16x8*)&sPw[m16 * SPS + 32 + quad * 8];

            // ---- O^T += V^T @ P^T ----
            #pragma unroll
            for (int nt = 0; nt < 4; nt++) {
                #pragma unroll
                for (int r = 0; r < 4; r++) oacc[qa][nt][r] *= alpha;
                oacc[qa][nt] = __builtin_amdgcn_mfma_f32_16x16x32_bf16(vf[nt][0], pf0, oacc[qa][nt], 0, 0, 0);
                oacc[qa][nt] = __builtin_amdgcn_mfma_f32_16x16x32_bf16(vf[nt][1], pf1, oacc[qa][nt], 0, 0, 0);
            }
        }
    }

    // ---- epilogue: O[q][h*64+d] = O^T/l ----
    #pragma unroll
    for (int qa = 0; qa < 2; qa++) {
        const float rl = 1.f / l_run[qa];
        #pragma unroll
        for (int nt = 0; nt < 4; nt++) {
            ushort_t pk[4];
            #pragma unroll
            for (int r = 0; r < 4; r++) pk[r] = f2bf(oacc[qa][nt][r] * rl);
            *(uint2*)&qkv[(size_t)qi[qa] * QKV_LD + h * 64 + nt * 16 + quad * 4] = *(uint2*)pk;
        }
    }
}

// ---------------------------------------------------------------------------
extern "C" void kernel_launch(void* const* d_in, const int* in_sizes, int n_in,
                              void* d_out, int out_size, void* d_ws, size_t ws_size,
                              hipStream_t stream)
{
    const float* x  = (const float*)d_in[0];
    // d_in[1] = mask (int32) — causal, handled analytically
    const float* wq = (const float*)d_in[2];
    const float* wk = (const float*)d_in[3];
    const float* wv = (const float*)d_in[4];
    const float* wo = (const float*)d_in[5];

    ushort_t* WT  = (ushort_t*)d_ws;                    // [3072][2048] bf16
    ushort_t* xb  = WT + (size_t)3072 * 2048;           // [2048][2048] bf16
    ushort_t* woT = xb;                                 // alias: xb dead after QKV GEMM
    ushort_t* qkv = xb + (size_t)2048 * 2048;           // [2048][3072] bf16
    ushort_t* Kr  = qkv + (size_t)SEQ * QKV_LD;         // [8][2048][64]
    ushort_t* Vt  = Kr + (size_t)NKV * SEQ * HD;        // [8][64][2048]

    dim3 blk(256);

    convert_kernel<<<(DIM * SEQ) / 1024, blk, 0, stream>>>(x, xb);
    transpose_kernel<<<dim3(32, 32), blk, 0, stream>>>(wq, WT, 2048);
    transpose_kernel<<<dim3(8, 32),  blk, 0, stream>>>(wk, WT + (size_t)2048 * 2048, 512);
    transpose_kernel<<<dim3(8, 32),  blk, 0, stream>>>(wv, WT + (size_t)2560 * 2048, 512);

    // Fused QKV projection: [2048,2048] x [2048,3072] -> qkv
    gemm_kernel<0><<<dim3(QKV_LD / 128, SEQ / 128), blk, 0, stream>>>(xb, WT, qkv, DIM, DIM, QKV_LD);

    // wo transpose (reuses xb region — must follow the QKV GEMM)
    transpose_kernel<<<dim3(32, 32), blk, 0, stream>>>(wo, woT, 2048);

    // RoPE: SEQ*40 slices, one wave each
    rope_kernel<<<(SEQ * 40 * 64) / 256, blk, 0, stream>>>(qkv, Kr);
    vtrans_kernel<<<NKV * (SEQ / 64), blk, 0, stream>>>(qkv, Vt);

    // Attention: 8 complementary band-pairs x 32 heads, 512-thread blocks
    attn_kernel<<<8 * NH, dim3(512), 0, stream>>>(qkv, Kr, Vt);

    // Output projection -> d_out fp32
    gemm_kernel<1><<<dim3(DIM / 128, SEQ / 128), blk, 0, stream>>>(qkv, woT, d_out, DIM, QKV_LD, DIM);
}

// Round 4
// 300.433 us; speedup vs baseline: 1.2571x; 1.0036x over previous
//
#include <hip/hip_runtime.h>
#include <hip/hip_bf16.h>

#define DIM 2048
#define SEQ 2048
#define NH 32
#define HD 64
#define NKV 8
#define QKV_LD 3072

typedef __attribute__((ext_vector_type(8))) short bf16x8;
typedef __attribute__((ext_vector_type(4))) float f32x4;
typedef __attribute__((ext_vector_type(2))) unsigned int uint2v;
typedef unsigned short ushort_t;

__device__ inline unsigned short f2bf(float f) {
    union { float f; unsigned int u; } v; v.f = f;
    unsigned int r = v.u + 0x7fffu + ((v.u >> 16) & 1u);
    return (unsigned short)(r >> 16);
}
__device__ inline float bf2f(ushort_t u) {
    union { unsigned int u; float f; } v; v.u = ((unsigned int)u) << 16; return v.f;
}

// async global->LDS, 16B per lane. LDS dest is wave-uniform base + lane*16.
__device__ inline void async_cp16(const void* g, void* l) {
    __builtin_amdgcn_global_load_lds(
        (const __attribute__((address_space(1))) unsigned int*)g,
        (__attribute__((address_space(3))) unsigned int*)l, 16, 0, 0);
}

// --- gfx950 register-only lane exchange (compiler builtins, hazard-safe) ----
__device__ inline void pswap32(unsigned int& a, unsigned int& b) {
    uint2v r = __builtin_amdgcn_permlane32_swap(a, b, false, false);
    a = r[0]; b = r[1];
}
__device__ inline void pswap16(unsigned int& a, unsigned int& b) {
    uint2v r = __builtin_amdgcn_permlane16_swap(a, b, false, false);
    a = r[0]; b = r[1];
}
// Wave reductions via swaps. The two outputs are {self, partner} per lane
// (in some order), so combining BOTH is direction-independent.
__device__ inline float wave_max(float x) {
    unsigned int a = __float_as_uint(x), b = a;
    uint2v r = __builtin_amdgcn_permlane16_swap(a, b, false, false);
    x = fmaxf(__uint_as_float(r[0]), __uint_as_float(r[1]));
    a = __float_as_uint(x); b = a;
    r = __builtin_amdgcn_permlane32_swap(a, b, false, false);
    return fmaxf(__uint_as_float(r[0]), __uint_as_float(r[1]));
}
__device__ inline float wave_sum(float x) {
    unsigned int a = __float_as_uint(x), b = a;
    uint2v r = __builtin_amdgcn_permlane16_swap(a, b, false, false);
    x = __uint_as_float(r[0]) + __uint_as_float(r[1]);
    a = __float_as_uint(x); b = a;
    r = __builtin_amdgcn_permlane32_swap(a, b, false, false);
    return __uint_as_float(r[0]) + __uint_as_float(r[1]);
}
__device__ inline unsigned int cvt_pk_bf16(float lo, float hi) {
    unsigned int r;
    asm volatile("v_cvt_pk_bf16_f32 %0, %1, %2" : "=v"(r) : "v"(lo), "v"(hi));
    return r;
}

// ---------------------------------------------------------------------------
// x fp32 -> bf16 (4 elems/thread)
// ---------------------------------------------------------------------------
__global__ __launch_bounds__(256) void convert_kernel(
    const float* __restrict__ X, ushort_t* __restrict__ Xb)
{
    int i = (blockIdx.x * 256 + threadIdx.x) * 4;
    float4 v = *(const float4*)(X + i);
    ushort_t o[4] = { f2bf(v.x), f2bf(v.y), f2bf(v.z), f2bf(v.w) };
    *(uint2*)(Xb + i) = *(uint2*)o;
}

// ---------------------------------------------------------------------------
// W fp32 [2048][N] -> WT bf16 [N][2048] (transpose + convert), 64x64 tiles.
// ---------------------------------------------------------------------------
__global__ __launch_bounds__(256) void transpose_kernel(
    const float* __restrict__ W, ushort_t* __restrict__ WT, int N)
{
    __shared__ __align__(16) ushort_t tile[64][72];
    const int n0 = blockIdx.x * 64, k0 = blockIdx.y * 64;
    const int t = threadIdx.x;
    {
        const int tk = t >> 4;
        const int tn = (t & 15) * 4;
        #pragma unroll
        for (int i = 0; i < 4; i++) {
            const int k = tk + i * 16;
            float4 v = *(const float4*)(W + (size_t)(k0 + k) * N + n0 + tn);
            tile[tn + 0][k] = f2bf(v.x);
            tile[tn + 1][k] = f2bf(v.y);
            tile[tn + 2][k] = f2bf(v.z);
            tile[tn + 3][k] = f2bf(v.w);
        }
    }
    __syncthreads();
    {
        const int tn = t >> 2;
        const int tk = (t & 3) * 16;
        uint4 a = *(const uint4*)&tile[tn][tk];
        uint4 b = *(const uint4*)&tile[tn][tk + 8];
        ushort_t* dst = WT + (size_t)(n0 + tn) * DIM + k0 + tk;
        *(uint4*)dst = a;
        *(uint4*)(dst + 8) = b;
    }
}

// ---------------------------------------------------------------------------
// GEMM m97-style: C[M,N] = A[M,K](bf16) * BT[N,K](bf16)^T.
// 128x128 tile / 256 threads, BK=32, global_load_lds staging (unpadded LDS).
// Grid (N/128, M/128). OUT_F32: fp32 epilogue to d_out.
// ---------------------------------------------------------------------------
template<int OUT_F32>
__global__ __launch_bounds__(256) void gemm_kernel(
    const ushort_t* __restrict__ A, const ushort_t* __restrict__ BT,
    void* __restrict__ Cout, int K, int lda, int ldo)
{
    __shared__ __align__(16) ushort_t sA[128 * 32];
    __shared__ __align__(16) ushort_t sB[128 * 32];
    const int tn = blockIdx.x * 128, tm = blockIdx.y * 128;
    const int t = threadIdx.x, wave = t >> 6, lane = t & 63;
    const int m16 = lane & 15, quad = lane >> 4;
    const int wr = (wave >> 1) * 64, wc = (wave & 1) * 64;
    const int srow = lane >> 2;
    const int sce = (lane & 3) * 8;

    f32x4 acc[4][4] = {};

    for (int k0 = 0; k0 < K; k0 += 32) {
        __syncthreads();
        #pragma unroll
        for (int p = 0; p < 2; p++) {
            const int j = wave * 2 + p;
            const int row = j * 16 + srow;
            async_cp16(A  + (size_t)(tm + row) * lda + k0 + sce, &sA[j * 512]);
            async_cp16(BT + (size_t)(tn + row) * K   + k0 + sce, &sB[j * 512]);
        }
        __syncthreads();
        bf16x8 af[4], bf[4];
        #pragma unroll
        for (int mt = 0; mt < 4; mt++)
            af[mt] = *(const bf16x8*)&sA[(wr + mt * 16 + m16) * 32 + quad * 8];
        #pragma unroll
        for (int nt = 0; nt < 4; nt++)
            bf[nt] = *(const bf16x8*)&sB[(wc + nt * 16 + m16) * 32 + quad * 8];
        #pragma unroll
        for (int mt = 0; mt < 4; mt++)
            #pragma unroll
            for (int nt = 0; nt < 4; nt++)
                acc[mt][nt] = __builtin_amdgcn_mfma_f32_16x16x32_bf16(af[mt], bf[nt], acc[mt][nt], 0, 0, 0);
    }

    #pragma unroll
    for (int mt = 0; mt < 4; mt++) {
        const int row = tm + wr + mt * 16 + quad * 4;
        #pragma unroll
        for (int nt = 0; nt < 4; nt++) {
            const int col = tn + wc + nt * 16 + m16;
            #pragma unroll
            for (int r = 0; r < 4; r++) {
                if (OUT_F32)
                    ((float*)Cout)[(size_t)(row + r) * ldo + col] = acc[mt][nt][r];
                else
                    ((ushort_t*)Cout)[(size_t)(row + r) * ldo + col] = f2bf(acc[mt][nt][r]);
            }
        }
    }
}

// ---------------------------------------------------------------------------
// RoPE, lane-per-element: one wave per 64-elem head slice, 1 shuffle/lane.
// Q (hh<32) is PRE-SCALED by 0.125*log2(e) so attention scores are already
// in exp2 domain (saves 2 muls/element in the attn inner loop).
// ---------------------------------------------------------------------------
#define QSCALE 0.18033688011112042f   // 0.125 * log2(e)
__global__ __launch_bounds__(256) void rope_kernel(ushort_t* qkv, ushort_t* __restrict__ Kr)
{
    const int gid = blockIdx.x * 256 + threadIdx.x;
    const int lane = gid & 63;
    const int idx = gid >> 6;              // slice index
    const int s = idx / 40;
    const int hh = idx - s * 40;

    const ushort_t* src;
    ushort_t* dst;
    const bool isq = (hh < 32);
    if (isq) {
        dst = qkv + (size_t)s * QKV_LD + hh * 64;
        src = dst;
    } else {
        src = qkv + (size_t)s * QKV_LD + 2048 + (hh - 32) * 64;
        dst = Kr + ((size_t)(hh - 32) * SEQ + s) * 64;
    }

    const float e = bf2f(src[lane]);
    const int i = lane & 31;
    const float freq = __expf(-(float)i * 0.28782313662425572f);  // ln(10000)/32
    const float ang = (float)s * freq;
    const float cv = cosf(ang), sv = sinf(ang);
    const int partner = (lane < 32) ? (2 * lane + 1) : (2 * (lane - 32));
    const float y = __shfl(e, partner, 64);
    float out = (lane < 32) ? (e * cv - y * sv) : (e * cv + y * sv);
    if (isq) out *= QSCALE;
    dst[lane] = f2bf(out);
}

// ---------------------------------------------------------------------------
// V transpose (tiled through LDS): Vt[kvh][d][s] = qkv[s][2560+kvh*64+d]
// ---------------------------------------------------------------------------
__global__ __launch_bounds__(256) void vtrans_kernel(
    const ushort_t* __restrict__ qkv, ushort_t* __restrict__ Vt)
{
    __shared__ __align__(16) ushort_t tile[64][72];
    const int kvh = blockIdx.x & 7;
    const int s0 = (blockIdx.x >> 3) * 64;
    const int t = threadIdx.x;
    {
        const int sr = t >> 3;
        const int d8 = (t & 7) * 8;
        #pragma unroll
        for (int i = 0; i < 2; i++) {
            const int s = sr + i * 32;
            ushort_t tmp[8];
            *(uint4*)tmp = *(const uint4*)(qkv + (size_t)(s0 + s) * QKV_LD + 2560 + kvh * 64 + d8);
            #pragma unroll
            for (int j = 0; j < 8; j++) tile[d8 + j][s] = tmp[j];
        }
    }
    __syncthreads();
    {
        const int dr = t >> 3;
        const int s8 = (t & 7) * 8;
        #pragma unroll
        for (int i = 0; i < 2; i++) {
            const int d = dr + i * 32;
            *(uint4*)(Vt + ((size_t)kvh * 64 + d) * SEQ + s0 + s8) = *(const uint4*)&tile[d][s8];
        }
    }
}

// ---------------------------------------------------------------------------
// Flash attention, S^T orientation, ZERO LDS (fully in-register softmax).
// Block = 512 threads (8 waves), no barriers. Waves 0-3: band 15-p (128 q),
// waves 4-7: band p -> per-CU work exactly uniform, grid 256 = 1 block/CU.
// Per wave: 2 query strips; K register-prefetched one tile ahead.
// P^T handoff to the PV MFMA is done IN REGISTERS:
//   lane(quad q, m16) holds S^T keys {16t+4q+r} for query m16; pack key-pairs
//   into words u[t][c] = w_global[8t+2q+c] = cvt_pk(e[2W], e[2W+1]); then
//   pswap32+pswap16 on (u[t],u[t+1]) yields, per dest quad q:
//   first reg = w[4q+c], second = w[4q+2+c]  (pf0 words W=4q+c,
//   pf1 words W=16+4q+c) == exact B-fragment layout for the PV MFMA
//   (pf[j] = P^T[key = quad*8+j][q = m16]), matching the old verified LDS path.
// Softmax in exp2 domain (Q pre-scaled); max-update deferred (THR=8).
// ---------------------------------------------------------------------------
__global__ __launch_bounds__(512, 2) void attn_kernel(
    ushort_t* qkv, const ushort_t* __restrict__ Kr, const ushort_t* __restrict__ Vt)
{
    const int t = threadIdx.x, wave = t >> 6, lane = t & 63;
    const int m16 = lane & 15, quad = lane >> 4;
    const int h = blockIdx.x & 31;
    const int p = blockIdx.x >> 5;             // pair index 0..7
    const int grp = wave >> 2;                 // 0: heavy band, 1: light band
    const int w4 = wave & 3;
    const int band = grp ? p : 15 - p;         // 128-query band
    const int kvh = h >> 2;

    const ushort_t* Krh = Kr + (size_t)kvh * SEQ * 64;   // [s][d]
    const ushort_t* Vth = Vt + (size_t)kvh * 64 * SEQ;   // [d][s]

    const int nkt = band * 2 + 2;

    // Two 16-query strips per wave: qa=0 -> lower 64 of band, qa=1 -> upper.
    int qi[2];
    bf16x8 qf[2][2];
    #pragma unroll
    for (int qa = 0; qa < 2; qa++) {
        qi[qa] = band * 128 + (w4 + qa * 4) * 16 + m16;
        const ushort_t* qp = qkv + (size_t)qi[qa] * QKV_LD + h * 64 + quad * 8;
        qf[qa][0] = *(const bf16x8*)qp;
        qf[qa][1] = *(const bf16x8*)(qp + 32);
    }

    f32x4 oacc[2][4] = {};                  // O^T: col=q(m16), row=d
    float m_run[2] = { -1e30f, -1e30f };
    float l_run[2] = { 0.f, 0.f };

    // Prologue: K fragments for tile 0 (only load that pays full latency).
    bf16x8 kf[4][2];
    #pragma unroll
    for (int knt = 0; knt < 4; knt++) {
        const ushort_t* kp = Krh + (size_t)(knt * 16 + m16) * 64 + quad * 8;
        kf[knt][0] = *(const bf16x8*)kp;
        kf[knt][1] = *(const bf16x8*)(kp + 32);
    }

    for (int kt = 0; kt < nkt; kt++) {
        const int kbase = kt * 64;
        const bool last = (kt == nkt - 1);

        // ---- QK^T for both strips while kf is live ----
        f32x4 sc[2][4] = {};
        __builtin_amdgcn_s_setprio(1);
        #pragma unroll
        for (int qa = 0; qa < 2; qa++) {
            if (qa == 0 && last) continue;   // last tile fully masked for lower strip
            #pragma unroll
            for (int knt = 0; knt < 4; knt++) {
                sc[qa][knt] = __builtin_amdgcn_mfma_f32_16x16x32_bf16(kf[knt][0], qf[qa][0], sc[qa][knt], 0, 0, 0);
                sc[qa][knt] = __builtin_amdgcn_mfma_f32_16x16x32_bf16(kf[knt][1], qf[qa][1], sc[qa][knt], 0, 0, 0);
            }
        }
        __builtin_amdgcn_s_setprio(0);

        // ---- V loads for this tile (consumed after softmax) ----
        bf16x8 vf[4][2];
        #pragma unroll
        for (int nt = 0; nt < 4; nt++) {
            const ushort_t* vp = Vth + (size_t)(nt * 16 + m16) * SEQ + kbase + quad * 8;
            vf[nt][0] = *(const bf16x8*)vp;
            vf[nt][1] = *(const bf16x8*)(vp + 32);
        }
        // ---- K prefetch for next tile (consumed next iteration) ----
        if (!last) {
            #pragma unroll
            for (int knt = 0; knt < 4; knt++) {
                const ushort_t* kp = Krh + (size_t)(kbase + 64 + knt * 16 + m16) * 64 + quad * 8;
                kf[knt][0] = *(const bf16x8*)kp;
                kf[knt][1] = *(const bf16x8*)(kp + 32);
            }
        }

        // ---- softmax + PV per strip ----
        #pragma unroll
        for (int qa = 0; qa < 2; qa++) {
            if (qa == 0 && last) continue;
            const bool domask = (qa == 0) ? (kt == nkt - 2) : last;

            float s[16];
            #pragma unroll
            for (int knt = 0; knt < 4; knt++)
                #pragma unroll
                for (int r = 0; r < 4; r++) {
                    float v = sc[qa][knt][r];           // already exp2-domain
                    if (domask && (kbase + knt * 16 + quad * 4 + r > qi[qa])) v = -1e30f;
                    s[knt * 4 + r] = v;
                }

            // per-lane max tree, then cross-lane via permlane swaps
            float x0 = fmaxf(s[0], s[1]),  x1 = fmaxf(s[2], s[3]);
            float x2 = fmaxf(s[4], s[5]),  x3 = fmaxf(s[6], s[7]);
            float x4 = fmaxf(s[8], s[9]),  x5 = fmaxf(s[10], s[11]);
            float x6 = fmaxf(s[12], s[13]), x7 = fmaxf(s[14], s[15]);
            float rmax = fmaxf(fmaxf(fmaxf(x0, x1), fmaxf(x2, x3)),
                               fmaxf(fmaxf(x4, x5), fmaxf(x6, x7)));
            rmax = wave_max(rmax);

            // deferred-max update (THR=8 in exp2 domain -> P <= 256);
            // rmax is wave-uniform here so the branch is uniform.
            if (rmax > m_run[qa] + 8.f) {
                const float mnew = fmaxf(m_run[qa], rmax);
                const float alpha = __builtin_amdgcn_exp2f(m_run[qa] - mnew);
                m_run[qa] = mnew;
                l_run[qa] *= alpha;
                #pragma unroll
                for (int nt = 0; nt < 4; nt++)
                    #pragma unroll
                    for (int r = 0; r < 4; r++) oacc[qa][nt][r] *= alpha;
            }
            const float m = m_run[qa];

            #pragma unroll
            for (int i = 0; i < 16; i++) s[i] = __builtin_amdgcn_exp2f(s[i] - m);
            float y0 = s[0] + s[1],  y1 = s[2] + s[3];
            float y2 = s[4] + s[5],  y3 = s[6] + s[7];
            float y4 = s[8] + s[9],  y5 = s[10] + s[11];
            float y6 = s[12] + s[13], y7 = s[14] + s[15];
            float ps = ((y0 + y1) + (y2 + y3)) + ((y4 + y5) + (y6 + y7));
            l_run[qa] += wave_sum(ps);

            // ---- P^T in registers: pack + permlane exchange ----
            // u[t][c] = w_global[8t+2q+c]; (t,t+1) swaps -> B-fragment words.
            unsigned int u00 = cvt_pk_bf16(s[0],  s[1]),  u01 = cvt_pk_bf16(s[2],  s[3]);
            unsigned int u10 = cvt_pk_bf16(s[4],  s[5]),  u11 = cvt_pk_bf16(s[6],  s[7]);
            unsigned int u20 = cvt_pk_bf16(s[8],  s[9]),  u21 = cvt_pk_bf16(s[10], s[11]);
            unsigned int u30 = cvt_pk_bf16(s[12], s[13]), u31 = cvt_pk_bf16(s[14], s[15]);
            pswap32(u00, u10); pswap16(u00, u10);   // -> w[4q+0], w[4q+2]
            pswap32(u01, u11); pswap16(u01, u11);   // -> w[4q+1], w[4q+3]
            pswap32(u20, u30); pswap16(u20, u30);   // -> w[16+4q+0], w[16+4q+2]
            pswap32(u21, u31); pswap16(u21, u31);   // -> w[16+4q+1], w[16+4q+3]
            union { unsigned int w[4]; bf16x8 v; } P0, P1;
            P0.w[0] = u00; P0.w[1] = u01; P0.w[2] = u10; P0.w[3] = u11;
            P1.w[0] = u20; P1.w[1] = u21; P1.w[2] = u30; P1.w[3] = u31;

            // ---- O^T += V^T @ P^T ----
            __builtin_amdgcn_s_setprio(1);
            #pragma unroll
            for (int nt = 0; nt < 4; nt++) {
                oacc[qa][nt] = __builtin_amdgcn_mfma_f32_16x16x32_bf16(vf[nt][0], P0.v, oacc[qa][nt], 0, 0, 0);
                oacc[qa][nt] = __builtin_amdgcn_mfma_f32_16x16x32_bf16(vf[nt][1], P1.v, oacc[qa][nt], 0, 0, 0);
            }
            __builtin_amdgcn_s_setprio(0);
        }
    }

    // ---- epilogue: O[q][h*64+d] = O^T/l ----
    #pragma unroll
    for (int qa = 0; qa < 2; qa++) {
        const float rl = 1.f / l_run[qa];
        #pragma unroll
        for (int nt = 0; nt < 4; nt++) {
            ushort_t pk[4];
            #pragma unroll
            for (int r = 0; r < 4; r++) pk[r] = f2bf(oacc[qa][nt][r] * rl);
            *(uint2*)&qkv[(size_t)qi[qa] * QKV_LD + h * 64 + nt * 16 + quad * 4] = *(uint2*)pk;
        }
    }
}

// ---------------------------------------------------------------------------
extern "C" void kernel_launch(void* const* d_in, const int* in_sizes, int n_in,
                              void* d_out, int out_size, void* d_ws, size_t ws_size,
                              hipStream_t stream)
{
    const float* x  = (const float*)d_in[0];
    // d_in[1] = mask (int32) — causal, handled analytically
    const float* wq = (const float*)d_in[2];
    const float* wk = (const float*)d_in[3];
    const float* wv = (const float*)d_in[4];
    const float* wo = (const float*)d_in[5];

    ushort_t* WT  = (ushort_t*)d_ws;                    // [3072][2048] bf16
    ushort_t* xb  = WT + (size_t)3072 * 2048;           // [2048][2048] bf16
    ushort_t* woT = xb;                                 // alias: xb dead after QKV GEMM
    ushort_t* qkv = xb + (size_t)2048 * 2048;           // [2048][3072] bf16
    ushort_t* Kr  = qkv + (size_t)SEQ * QKV_LD;         // [8][2048][64]
    ushort_t* Vt  = Kr + (size_t)NKV * SEQ * HD;        // [8][64][2048]

    dim3 blk(256);

    convert_kernel<<<(DIM * SEQ) / 1024, blk, 0, stream>>>(x, xb);
    transpose_kernel<<<dim3(32, 32), blk, 0, stream>>>(wq, WT, 2048);
    transpose_kernel<<<dim3(8, 32),  blk, 0, stream>>>(wk, WT + (size_t)2048 * 2048, 512);
    transpose_kernel<<<dim3(8, 32),  blk, 0, stream>>>(wv, WT + (size_t)2560 * 2048, 512);

    // Fused QKV projection: [2048,2048] x [2048,3072] -> qkv
    gemm_kernel<0><<<dim3(QKV_LD / 128, SEQ / 128), blk, 0, stream>>>(xb, WT, qkv, DIM, DIM, QKV_LD);

    // wo transpose (reuses xb region — must follow the QKV GEMM)
    transpose_kernel<<<dim3(32, 32), blk, 0, stream>>>(wo, woT, 2048);

    // RoPE: SEQ*40 slices, one wave each (Q pre-scaled to exp2 domain)
    rope_kernel<<<(SEQ * 40 * 64) / 256, blk, 0, stream>>>(qkv, Kr);
    vtrans_kernel<<<NKV * (SEQ / 64), blk, 0, stream>>>(qkv, Vt);

    // Attention: 8 complementary band-pairs x 32 heads, 512-thread blocks
    attn_kernel<<<8 * NH, dim3(512), 0, stream>>>(qkv, Kr, Vt);

    // Output projection -> d_out fp32
    gemm_kernel<1><<<dim3(DIM / 128, SEQ / 128), blk, 0, stream>>>(qkv, woT, d_out, DIM, QKV_LD, DIM);
}